// Round 1
// baseline (97.546 us; speedup 1.0000x reference)
//
#include <hip/hip_runtime.h>
#include <hip/hip_bf16.h>

typedef __bf16 bf16x8 __attribute__((ext_vector_type(8)));
typedef float f32x16 __attribute__((ext_vector_type(16)));
typedef unsigned int u32x4 __attribute__((ext_vector_type(4)));
typedef unsigned short u16;

// Problem constants: T=16, N=128, D=512, M=4096, NT=2048, TEMP=0.1
// ws layout: zn bf16[4096*512] (4 MiB) | expsum f32[4096] | possum f32[4096]

// ---------------------------------------------------------------- normalize
__global__ void nrm_kernel(const float* __restrict__ z, u16* __restrict__ zn,
                           float* __restrict__ expsum, float* __restrict__ possum) {
    int row = blockIdx.x;          // 4096 rows
    int tid = threadIdx.x;         // 128 threads, 4 floats each
    float4 v = ((const float4*)(z + row * 512))[tid];
    float ss = v.x * v.x + v.y * v.y + v.z * v.z + v.w * v.w;
#pragma unroll
    for (int off = 32; off; off >>= 1) ss += __shfl_down(ss, off, 64);
    __shared__ float red[2];
    if ((tid & 63) == 0) red[tid >> 6] = ss;
    __syncthreads();
    float norm = fmaxf(sqrtf(red[0] + red[1]), 1e-8f);  // matches ref clamp
    float sc = 1.0f / norm;
    __hip_bfloat16 b[4];
    b[0] = __float2bfloat16(v.x * sc);
    b[1] = __float2bfloat16(v.y * sc);
    b[2] = __float2bfloat16(v.z * sc);
    b[3] = __float2bfloat16(v.w * sc);
    uint2 p;
    __builtin_memcpy(&p, b, 8);
    ((uint2*)(zn + row * 512))[tid] = p;
    if (tid == 0) { expsum[row] = 0.f; possum[row] = 0.f; }
}

// ---------------------------------------------------------------- positives
// Group g (128 groups): rows {g*16..g*16+15} U {2048+g*16..+15}. One wave
// computes the 32x32 Gram via MFMA (same frag as A and B => Z Z^T), masks the
// diagonal, row-reduces; possum[i] = 10 * sum_{j in group, j!=i} zn_i.zn_j
__global__ void pos_kernel(const u16* __restrict__ zn, float* __restrict__ possum) {
    int g = blockIdx.x;
    int l = threadIdx.x;           // 64
    int u = l & 31, h = l >> 5;
    int grow = (u < 16) ? (g * 16 + u) : (2048 + g * 16 + (u - 16));
    const u32x4* src = (const u32x4*)(zn + grow * 512);
    f32x16 acc = {};
#pragma unroll
    for (int kc = 0; kc < 32; ++kc) {
        bf16x8 f = __builtin_bit_cast(bf16x8, src[h + 2 * kc]);
        acc = __builtin_amdgcn_mfma_f32_32x32x16_bf16(f, f, acc, 0, 0, 0);
    }
#pragma unroll
    for (int r = 0; r < 16; ++r) {
        int rrow = (r & 3) + 8 * (r >> 2) + 4 * h;   // C/D: col=lane&31, row=(reg&3)+8*(reg>>2)+4*(lane>>5)
        float v = (rrow == u) ? 0.f : acc[r];        // drop diagonal
        v += __shfl_xor(v, 1, 64);
        v += __shfl_xor(v, 2, 64);
        v += __shfl_xor(v, 4, 64);
        v += __shfl_xor(v, 8, 64);
        v += __shfl_xor(v, 16, 64);
        if (u == 0) {
            int gr = (rrow < 16) ? (g * 16 + rrow) : (2048 + g * 16 + (rrow - 16));
            possum[gr] = v * 10.0f;
        }
    }
}

// ---------------------------------------------------------------- fused GEMM
// 4 waves/WG; wave owns 32 rows, A (32x512 bf16) in 128 VGPRs. Col chunk 256
// per WG, staged in LDS 32 cols at a time ([col][k], stride 520 bf16 to spread
// bank groups). expacc[16] per lane accumulates exp(10*dot) per (row,col).
__global__ __launch_bounds__(256, 2) void gemm_kernel(const u16* __restrict__ zn,
                                                      float* __restrict__ expsum) {
    __shared__ u16 Bt[32 * 520];   // 33280 B
    int wave = threadIdx.x >> 6;
    int l = threadIdx.x & 63;
    int m = l & 31, h = l >> 5;    // A row-in-tile / k-half
    int rowbase = blockIdx.x * 128 + wave * 32;
    int colchunk = blockIdx.y * 256;

    // A fragments, full K=512: k = h*8 + kc*16 + j  (j=0..7 contiguous, 16B)
    u32x4 a[32];
    const u32x4* arow = (const u32x4*)(zn + (rowbase + m) * 512);
#pragma unroll
    for (int kc = 0; kc < 32; ++kc) a[kc] = arow[h + 2 * kc];

    float expacc[16];
#pragma unroll
    for (int r = 0; r < 16; ++r) expacc[r] = 0.f;

    int c = threadIdx.x >> 3;      // staging: col 0..31
    int g0 = threadIdx.x & 7;      // granule phase

    for (int ct = 0; ct < 8; ++ct) {
        int colbase = colchunk + ct * 32;
        __syncthreads();           // protect previous tile's reads
        const u32x4* src = (const u32x4*)(zn + (colbase + c) * 512);
        u32x4* dst = (u32x4*)(Bt + c * 520);
#pragma unroll
        for (int i = 0; i < 8; ++i) dst[g0 + 8 * i] = src[g0 + 8 * i];
        __syncthreads();

        f32x16 acc = {};
        const u32x4* brow = (const u32x4*)(Bt + m * 520);   // col n = lane&31
#pragma unroll
        for (int kc = 0; kc < 32; ++kc) {
            bf16x8 bf = __builtin_bit_cast(bf16x8, brow[h + 2 * kc]);
            acc = __builtin_amdgcn_mfma_f32_32x32x16_bf16(
                __builtin_bit_cast(bf16x8, a[kc]), bf, acc, 0, 0, 0);
        }
        if (colbase == rowbase) {  // wave-uniform: the one aligned diagonal tile
#pragma unroll
            for (int r = 0; r < 16; ++r) {
                int rrow = (r & 3) + 8 * (r >> 2) + 4 * h;
                if (rrow != m) expacc[r] += __expf(acc[r] * 10.0f);
            }
        } else {
#pragma unroll
            for (int r = 0; r < 16; ++r) expacc[r] += __expf(acc[r] * 10.0f);
        }
    }
    // reduce over the 32 columns (lanes within each half), then one atomic/row
#pragma unroll
    for (int r = 0; r < 16; ++r) {
        float v = expacc[r];
        v += __shfl_xor(v, 1, 64);
        v += __shfl_xor(v, 2, 64);
        v += __shfl_xor(v, 4, 64);
        v += __shfl_xor(v, 8, 64);
        v += __shfl_xor(v, 16, 64);
        if (m == 0) {
            int rrow = (r & 3) + 8 * (r >> 2) + 4 * h;
            atomicAdd(&expsum[rowbase + rrow], v);
        }
    }
}

// ---------------------------------------------------------------- finalize
__global__ void fin_kernel(const float* __restrict__ expsum,
                           const float* __restrict__ possum, float* __restrict__ out) {
    int tid = threadIdx.x;         // 1024
    float s = 0.f;
    for (int i = tid; i < 4096; i += 1024)
        s += __logf(expsum[i]) - possum[i] * (1.0f / 31.0f);
#pragma unroll
    for (int off = 32; off; off >>= 1) s += __shfl_down(s, off, 64);
    __shared__ float red[16];
    if ((tid & 63) == 0) red[tid >> 6] = s;
    __syncthreads();
    if (tid == 0) {
        float t = 0.f;
#pragma unroll
        for (int i = 0; i < 16; ++i) t += red[i];
        out[0] = t * (1.0f / 4096.0f);
    }
}

extern "C" void kernel_launch(void* const* d_in, const int* in_sizes, int n_in,
                              void* d_out, int out_size, void* d_ws, size_t ws_size,
                              hipStream_t stream) {
    const float* z = (const float*)d_in[0];
    // d_in[1] (done) is provably dead: positive_mask reduces to block-diag + eye.
    u16* zn = (u16*)d_ws;
    float* expsum = (float*)((char*)d_ws + (4u << 20));
    float* possum = expsum + 4096;
    float* out = (float*)d_out;

    nrm_kernel<<<4096, 128, 0, stream>>>(z, zn, expsum, possum);
    pos_kernel<<<128, 64, 0, stream>>>(zn, possum);
    gemm_kernel<<<dim3(32, 16), 256, 0, stream>>>(zn, expsum);
    fin_kernel<<<1, 1024, 0, stream>>>(expsum, possum, out);
}